// Round 1
// baseline (26515.945 us; speedup 1.0000x reference)
//
#include <hip/hip_runtime.h>
#include <hip/hip_bf16.h>
#include <hip/hip_cooperative_groups.h>

namespace cg = cooperative_groups;

#define TT  512   // timesteps
#define BB  256   // batch
#define IND 64    // input dim
#define HH  512   // hidden dim
#define OD  64    // output dim

typedef __bf16 v8bf __attribute__((ext_vector_type(8)));
typedef float  v4f  __attribute__((ext_vector_type(4)));

struct Params {
  const __bf16 *xb, *Wi0, *Wh0, *Wi1, *Wh1, *Wlin;
  const float  *bsum0, *bsum1, *blin;
  __bf16 *h0, *h1;          // double-buffered [2][BB*HH], slot = t&1
  float  *c0, *c1;          // [BB*HH]
  float  *out;              // [BB][TT*OD]
};

__device__ __forceinline__ float sigm(float x) { return 1.f / (1.f + __expf(-x)); }
__device__ __forceinline__ float tanh_fast(float x) {
  // 1 - 2/(e^{2x}+1): saturates correctly for |x| large (no inf/inf NaN)
  float e = __expf(2.f * x);
  return 1.f - 2.f / (e + 1.f);
}
__device__ __forceinline__ v4f mfma16(v8bf a, v8bf b, v4f c) {
  return __builtin_amdgcn_mfma_f32_16x16x32_bf16(a, b, c, 0, 0, 0);
}

// ---------------- prep: fp32 -> bf16 weights/x, combined biases, zero states ---
__global__ void __launch_bounds__(256) prep_kernel(
    const float* x, const float* Wi0, const float* Wh0, const float* bi0, const float* bh0,
    const float* Wi1, const float* Wh1, const float* bi1, const float* bh1, const float* Wlin,
    __bf16* xb, __bf16* Wi0b, __bf16* Wh0b, __bf16* Wi1b, __bf16* Wh1b, __bf16* Wlinb,
    float* bsum0, float* bsum1, __bf16* h0, __bf16* h1, float* c0, float* c1) {
  size_t tid = (size_t)blockIdx.x * blockDim.x + threadIdx.x;
  size_t np  = (size_t)gridDim.x * blockDim.x;
  for (size_t i = tid; i < (size_t)TT * BB * IND; i += np) xb[i]   = (__bf16)x[i];
  for (size_t i = tid; i < (size_t)4 * HH * IND;  i += np) Wi0b[i] = (__bf16)Wi0[i];
  for (size_t i = tid; i < (size_t)4 * HH * HH;   i += np) Wh0b[i] = (__bf16)Wh0[i];
  for (size_t i = tid; i < (size_t)4 * HH * HH;   i += np) Wi1b[i] = (__bf16)Wi1[i];
  for (size_t i = tid; i < (size_t)4 * HH * HH;   i += np) Wh1b[i] = (__bf16)Wh1[i];
  for (size_t i = tid; i < (size_t)OD * HH;       i += np) Wlinb[i] = (__bf16)Wlin[i];
  for (size_t i = tid; i < (size_t)4 * HH; i += np) {
    bsum0[i] = bi0[i] + bh0[i];
    bsum1[i] = bi1[i] + bh1[i];
  }
  for (size_t i = tid; i < (size_t)2 * BB * HH; i += np) { h0[i] = (__bf16)0.f; h1[i] = (__bf16)0.f; }
  for (size_t i = tid; i < (size_t)BB * HH;     i += np) { c0[i] = 0.f; c1[i] = 0.f; }
}

// ---------------- main cooperative kernel -------------------------------------
// Phase p: layer0 computes t=p (blocks 128..191), layer1 computes t=p-1
// (blocks 0..127), linear computes t=p-2 (blocks 192..195). One grid.sync per
// phase; every cross-stage dependency crosses exactly one sync.
__global__ void __launch_bounds__(256, 1) lstm_coop(Params P) {
  cg::grid_group grid = cg::this_grid();
  __shared__ float lds[64 * 128];  // 32 KB gate-exchange tile

  const int bid  = blockIdx.x;
  const int tid  = threadIdx.x;
  const int wid  = tid >> 6;       // wave 0..3  (= gate index for gemm waves)
  const int lane = tid & 63;
  const int l16  = lane & 15;
  const int quad = lane >> 4;

  for (int p = 0; p < TT + 2; ++p) {
    if (bid < 128) {
      // ---------------- layer 1 : gates1 = h0_t @ Wi1^T + h1_{t-1} @ Wh1^T ----
      const int t = p - 1;
      if (t >= 0 && t < TT) {
        const int m0 = (bid >> 5) * 64;      // batch tile
        const int j0 = (bid & 31) * 16;      // hidden-unit chunk
        const __bf16* A0 = P.h0 + (size_t)(t & 1) * (BB * HH);        // h0_t
        const __bf16* A1 = P.h1 + (size_t)((t + 1) & 1) * (BB * HH);  // h1_{t-1}
        const int n0 = wid * HH + j0;        // this wave's gate column base

        v4f acc[4];
        #pragma unroll
        for (int s = 0; s < 4; ++s) acc[s] = (v4f){0.f, 0.f, 0.f, 0.f};

        #pragma unroll
        for (int src = 0; src < 2; ++src) {
          const __bf16* Arow = (src == 0 ? A0 : A1) + (size_t)(m0 + l16) * HH + quad * 8;
          const __bf16* Wrow = (src == 0 ? P.Wi1 : P.Wh1) + (size_t)(n0 + l16) * HH + quad * 8;
          #pragma unroll 4
          for (int k0 = 0; k0 < HH; k0 += 32) {
            v8bf bfrag = *(const v8bf*)(Wrow + k0);
            #pragma unroll
            for (int s = 0; s < 4; ++s) {
              v8bf afrag = *(const v8bf*)(Arow + (size_t)(s * 16) * HH + k0);
              acc[s] = mfma16(afrag, bfrag, acc[s]);
            }
          }
        }
        // gate exchange: wave g owns cols [g*16, g*16+16)
        #pragma unroll
        for (int s = 0; s < 4; ++s)
          #pragma unroll
          for (int r = 0; r < 4; ++r)
            lds[(s * 16 + quad * 4 + r) * 64 + wid * 16 + l16] = acc[s][r];
        __syncthreads();

        const size_t slotw = (size_t)(t & 1) * (BB * HH);
        for (int e = tid; e < 64 * 16; e += 256) {
          const int rr = e >> 4, jj = e & 15;
          const int j = j0 + jj;
          const size_t idx = (size_t)(m0 + rr) * HH + j;
          float iv = lds[rr * 64 +      jj] + P.bsum1[j];
          float fv = lds[rr * 64 + 16 + jj] + P.bsum1[HH + j];
          float gv = lds[rr * 64 + 32 + jj] + P.bsum1[2 * HH + j];
          float ov = lds[rr * 64 + 48 + jj] + P.bsum1[3 * HH + j];
          float cn = sigm(fv) * P.c1[idx] + sigm(iv) * tanh_fast(gv);
          P.c1[idx] = cn;
          P.h1[slotw + idx] = (__bf16)(sigm(ov) * tanh_fast(cn));
        }
      }
    } else if (bid < 192) {
      // ---------------- layer 0 : gates0 = x_t @ Wi0^T + h0_{t-1} @ Wh0^T -----
      const int t = p;
      if (t < TT) {
        const int k2 = bid - 128;
        const int m0 = (k2 >> 4) * 64;
        const int j0 = (k2 & 15) * 32;       // 32 hidden units -> 2 n-tiles/gate
        const __bf16* Ax = P.xb + (size_t)t * (BB * IND) + (size_t)(m0 + l16) * IND + quad * 8;
        const __bf16* Ah = P.h0 + (size_t)((t + 1) & 1) * (BB * HH) + (size_t)(m0 + l16) * HH + quad * 8;
        const __bf16* W0 = P.Wi0 + (size_t)(wid * HH + j0 + l16) * IND + quad * 8;
        const __bf16* Wh = P.Wh0 + (size_t)(wid * HH + j0 + l16) * HH + quad * 8;

        v4f acc[2][4];
        #pragma unroll
        for (int n = 0; n < 2; ++n)
          #pragma unroll
          for (int s = 0; s < 4; ++s) acc[n][s] = (v4f){0.f, 0.f, 0.f, 0.f};

        #pragma unroll
        for (int k0 = 0; k0 < IND; k0 += 32) {   // x contribution, K=64
          v8bf b0 = *(const v8bf*)(W0 + k0);
          v8bf b1 = *(const v8bf*)(W0 + (size_t)16 * IND + k0);
          #pragma unroll
          for (int s = 0; s < 4; ++s) {
            v8bf af = *(const v8bf*)(Ax + (size_t)(s * 16) * IND + k0);
            acc[0][s] = mfma16(af, b0, acc[0][s]);
            acc[1][s] = mfma16(af, b1, acc[1][s]);
          }
        }
        #pragma unroll 2
        for (int k0 = 0; k0 < HH; k0 += 32) {    // recurrent contribution, K=512
          v8bf b0 = *(const v8bf*)(Wh + k0);
          v8bf b1 = *(const v8bf*)(Wh + (size_t)16 * HH + k0);
          #pragma unroll
          for (int s = 0; s < 4; ++s) {
            v8bf af = *(const v8bf*)(Ah + (size_t)(s * 16) * HH + k0);
            acc[0][s] = mfma16(af, b0, acc[0][s]);
            acc[1][s] = mfma16(af, b1, acc[1][s]);
          }
        }
        #pragma unroll
        for (int nt = 0; nt < 2; ++nt)
          #pragma unroll
          for (int s = 0; s < 4; ++s)
            #pragma unroll
            for (int r = 0; r < 4; ++r)
              lds[(s * 16 + quad * 4 + r) * 128 + wid * 32 + nt * 16 + l16] = acc[nt][s][r];
        __syncthreads();

        const size_t slotw = (size_t)(t & 1) * (BB * HH);
        for (int e = tid; e < 64 * 32; e += 256) {
          const int rr = e >> 5, jj = e & 31;
          const int j = j0 + jj;
          const size_t idx = (size_t)(m0 + rr) * HH + j;
          float iv = lds[rr * 128 +      jj] + P.bsum0[j];
          float fv = lds[rr * 128 + 32 + jj] + P.bsum0[HH + j];
          float gv = lds[rr * 128 + 64 + jj] + P.bsum0[2 * HH + j];
          float ov = lds[rr * 128 + 96 + jj] + P.bsum0[3 * HH + j];
          float cn = sigm(fv) * P.c0[idx] + sigm(iv) * tanh_fast(gv);
          P.c0[idx] = cn;
          P.h0[slotw + idx] = (__bf16)(sigm(ov) * tanh_fast(cn));
        }
      }
    } else if (bid < 196) {
      // ---------------- output linear : out_t = h1_t @ Wlin^T + blin ----------
      const int t = p - 2;
      if (t >= 0) {
        const int m0 = (bid - 192) * 64;
        const __bf16* Arow = P.h1 + (size_t)(t & 1) * (BB * HH)
                             + (size_t)(m0 + wid * 16 + l16) * HH + quad * 8;
        const __bf16* Wrow = P.Wlin + (size_t)l16 * HH + quad * 8;

        v4f acc[4];
        #pragma unroll
        for (int nt = 0; nt < 4; ++nt) acc[nt] = (v4f){0.f, 0.f, 0.f, 0.f};
        #pragma unroll 4
        for (int k0 = 0; k0 < HH; k0 += 32) {
          v8bf af = *(const v8bf*)(Arow + k0);
          #pragma unroll
          for (int nt = 0; nt < 4; ++nt) {
            v8bf bf = *(const v8bf*)(Wrow + (size_t)(nt * 16) * HH + k0);
            acc[nt] = mfma16(af, bf, acc[nt]);
          }
        }
        #pragma unroll
        for (int nt = 0; nt < 4; ++nt) {
          const int col = nt * 16 + l16;
          const float bb = P.blin[col];
          #pragma unroll
          for (int r = 0; r < 4; ++r) {
            const int b = m0 + wid * 16 + quad * 4 + r;
            P.out[(size_t)b * (TT * OD) + (size_t)t * OD + col] = acc[nt][r] + bb;
          }
        }
      }
    }
    grid.sync();
  }
}

// ---------------- host ---------------------------------------------------------
extern "C" void kernel_launch(void* const* d_in, const int* in_sizes, int n_in,
                              void* d_out, int out_size, void* d_ws, size_t ws_size,
                              hipStream_t stream) {
  const float* x    = (const float*)d_in[0];
  const float* Wi0  = (const float*)d_in[1];
  const float* Wh0  = (const float*)d_in[2];
  const float* bi0  = (const float*)d_in[3];
  const float* bh0  = (const float*)d_in[4];
  const float* Wi1  = (const float*)d_in[5];
  const float* Wh1  = (const float*)d_in[6];
  const float* bi1  = (const float*)d_in[7];
  const float* bh1  = (const float*)d_in[8];
  const float* Wlin = (const float*)d_in[9];
  const float* blin = (const float*)d_in[10];
  // d_in[11] = future (always 0 in this benchmark)

  char* base = (char*)d_ws;
  size_t off = 0;
  auto take = [&](size_t nbytes) {
    void* p = base + off;
    off = (off + nbytes + 255) & ~(size_t)255;
    return p;
  };
  __bf16* xb    = (__bf16*)take(sizeof(__bf16) * (size_t)TT * BB * IND);
  __bf16* Wi0b  = (__bf16*)take(sizeof(__bf16) * 4 * HH * IND);
  __bf16* Wh0b  = (__bf16*)take(sizeof(__bf16) * 4 * HH * HH);
  __bf16* Wi1b  = (__bf16*)take(sizeof(__bf16) * 4 * HH * HH);
  __bf16* Wh1b  = (__bf16*)take(sizeof(__bf16) * 4 * HH * HH);
  __bf16* Wlinb = (__bf16*)take(sizeof(__bf16) * OD * HH);
  float*  bsum0 = (float*)take(sizeof(float) * 4 * HH);
  float*  bsum1 = (float*)take(sizeof(float) * 4 * HH);
  __bf16* h0    = (__bf16*)take(sizeof(__bf16) * 2 * BB * HH);
  __bf16* h1    = (__bf16*)take(sizeof(__bf16) * 2 * BB * HH);
  float*  c0    = (float*)take(sizeof(float) * BB * HH);
  float*  c1    = (float*)take(sizeof(float) * BB * HH);

  prep_kernel<<<dim3(1024), dim3(256), 0, stream>>>(
      x, Wi0, Wh0, bi0, bh0, Wi1, Wh1, bi1, bh1, Wlin,
      xb, Wi0b, Wh0b, Wi1b, Wh1b, Wlinb, bsum0, bsum1, h0, h1, c0, c1);

  Params P;
  P.xb = xb; P.Wi0 = Wi0b; P.Wh0 = Wh0b; P.Wi1 = Wi1b; P.Wh1 = Wh1b; P.Wlin = Wlinb;
  P.bsum0 = bsum0; P.bsum1 = bsum1; P.blin = blin;
  P.h0 = h0; P.h1 = h1; P.c0 = c0; P.c1 = c1;
  P.out = (float*)d_out;

  void* kargs[] = { (void*)&P };
  hipLaunchCooperativeKernel(reinterpret_cast<void*>(lstm_coop), dim3(196), dim3(256),
                             kargs, 0, stream);
}

// Round 3
// 18976.370 us; speedup vs baseline: 1.3973x; 1.3973x over previous
//
#include <hip/hip_runtime.h>
#include <hip/hip_bf16.h>

#define TT  512
#define BB  256
#define IND 64
#define HH  512
#define OD  64
#define BBHH (BB * HH)
#define FSTRIDE 16   // ints per flag line (64B padding)

typedef __bf16 v8bf  __attribute__((ext_vector_type(8)));
typedef float  v4f   __attribute__((ext_vector_type(4)));
typedef float  v16f  __attribute__((ext_vector_type(16)));

struct Params {
  const __bf16 *xb, *Wi0, *Wh0, *Wi1, *Wh1, *Wlin;
  const float  *bsum0, *bsum1, *blin;
  __bf16 *h0, *h1;          // 4-slot ring buffers [4][BB*HH], slot = t & 3
  int *f0, *f1, *fL;        // per-(step, row-group) flags, padded by FSTRIDE
  float *out;               // [BB][TT*OD]
};

__device__ __forceinline__ float sigm(float x) { return 1.f / (1.f + __expf(-x)); }
__device__ __forceinline__ float tanh_fast(float x) {
  float e = __expf(2.f * x);
  return 1.f - 2.f / (e + 1.f);
}
__device__ __forceinline__ v4f mfma16(v8bf a, v8bf b, v4f c) {
  return __builtin_amdgcn_mfma_f32_16x16x32_bf16(a, b, c, 0, 0, 0);
}
__device__ __forceinline__ v16f mfma32(v8bf a, v8bf b, v16f c) {
  return __builtin_amdgcn_mfma_f32_32x32x16_bf16(a, b, c, 0, 0, 0);
}

// Consumer wait: leader spins on agent-scope atomic loads, then block barrier
// + acquire fence (invalidate caches so h-state loads see producer's data).
__device__ __forceinline__ void wait2(const int* fa, int ta, const int* fb, int tb) {
  if (threadIdx.x == 0) {
    if (fa) while (__hip_atomic_load(fa, __ATOMIC_RELAXED, __HIP_MEMORY_SCOPE_AGENT) < ta) {}
    if (fb) while (__hip_atomic_load(fb, __ATOMIC_RELAXED, __HIP_MEMORY_SCOPE_AGENT) < tb) {}
  }
  __syncthreads();
  __builtin_amdgcn_fence(__ATOMIC_ACQUIRE, "agent");
}
// Producer signal: every thread release-fences its stores, barrier, leader bumps flag.
__device__ __forceinline__ void signal(int* f) {
  __threadfence();
  __syncthreads();
  if (threadIdx.x == 0)
    __hip_atomic_fetch_add(f, 1, __ATOMIC_RELAXED, __HIP_MEMORY_SCOPE_AGENT);
}

// ---------------- prep: fp32 -> bf16, combined biases, zero states/flags -------
__global__ void __launch_bounds__(256) prep_kernel(
    const float* x, const float* Wi0, const float* Wh0, const float* bi0, const float* bh0,
    const float* Wi1, const float* Wh1, const float* bi1, const float* bh1, const float* Wlin,
    __bf16* xb, __bf16* Wi0b, __bf16* Wh0b, __bf16* Wi1b, __bf16* Wh1b, __bf16* Wlinb,
    float* bsum0, float* bsum1, __bf16* h0, __bf16* h1, int* flags) {
  size_t tid = (size_t)blockIdx.x * blockDim.x + threadIdx.x;
  size_t np  = (size_t)gridDim.x * blockDim.x;
  for (size_t i = tid; i < (size_t)TT * BB * IND; i += np) xb[i]    = (__bf16)x[i];
  for (size_t i = tid; i < (size_t)4 * HH * IND;  i += np) Wi0b[i]  = (__bf16)Wi0[i];
  for (size_t i = tid; i < (size_t)4 * HH * HH;   i += np) Wh0b[i]  = (__bf16)Wh0[i];
  for (size_t i = tid; i < (size_t)4 * HH * HH;   i += np) Wi1b[i]  = (__bf16)Wi1[i];
  for (size_t i = tid; i < (size_t)4 * HH * HH;   i += np) Wh1b[i]  = (__bf16)Wh1[i];
  for (size_t i = tid; i < (size_t)OD * HH;       i += np) Wlinb[i] = (__bf16)Wlin[i];
  for (size_t i = tid; i < (size_t)4 * HH; i += np) {
    bsum0[i] = bi0[i] + bh0[i];
    bsum1[i] = bi1[i] + bh1[i];
  }
  for (size_t i = tid; i < (size_t)4 * BBHH; i += np) { h0[i] = (__bf16)0.f; h1[i] = (__bf16)0.f; }
  for (size_t i = tid; i < (size_t)3 * TT * 4 * FSTRIDE; i += np) flags[i] = 0;
}

// ---------------- persistent flag-synced kernel --------------------------------
// bid 0..127  : layer1  (8 m-tiles x 32 rows) x (16 j-chunks x 32 cols/gate)
// bid 128..191: layer0  (4 m-tiles x 64 rows) x (16 j-chunks x 32 cols/gate)
// bid 192..199: linear  (8 m-tiles x 32 rows)
// Weights persist in VGPRs. Flags are per (step, 64-row group):
//   f0[t*4+g]: +1 per layer0 block (target 16)
//   f1[t*4+g]: +1 per layer1 block (target 32)
//   fL[t*4+g]: +1 per linear block (target 2)
__global__ void __launch_bounds__(256, 1) lstm_persist(Params P) {
  __shared__ __align__(16) __bf16 sA[32 * 72 * 8];   // 36,864 B (layer0's max)
  float* xch = (float*)sA;                           // epilogue exchange overlay

  const int bid  = blockIdx.x;
  const int tid  = threadIdx.x;
  const int lane = tid & 63;
  const int wid  = tid >> 6;        // wave = gate (layers) or col-group (linear)
  const int khi  = lane >> 5;       // k-half within a K=16 step
  const int l32  = lane & 31;

  if (bid < 128) {
    // =================== LAYER 1 : h1_{t-1} @ Wh1^T  +  h0_t @ Wi1^T ==========
    // Split-K: GEMM over h1_{t-1} runs BEFORE waiting for h0_t (overlap).
    const int m0  = (bid >> 4) * 32;
    const int j0  = (bid & 15) * 32;
    const int grp = m0 >> 6;
    const int n   = wid * HH + j0 + l32;         // weight row = gate column
    v8bf breg[64];                               // 256 VGPRs, persistent
    {
      const __bf16* Wh = P.Wh1 + (size_t)n * HH + khi * 8;
      #pragma unroll
      for (int ks = 0; ks < 32; ++ks) breg[ks]      = *(const v8bf*)(Wh + ks * 16);
      const __bf16* Wi = P.Wi1 + (size_t)n * HH + khi * 8;
      #pragma unroll
      for (int ks = 0; ks < 32; ++ks) breg[32 + ks] = *(const v8bf*)(Wi + ks * 16);
    }
    const int jj = tid & 31, rr0 = tid >> 5;
    const int j = j0 + jj;
    const float bI = P.bsum1[j], bF = P.bsum1[HH + j],
                bG = P.bsum1[2 * HH + j], bO = P.bsum1[3 * HH + j];
    float creg[4] = {0.f, 0.f, 0.f, 0.f};
    const int h = l32 & 7;
    const __bf16* abase = sA + (size_t)l32 * 64 * 8;

    for (int t = 0; t < TT; ++t) {
      // h1_{t-1} ready (own group); back-pressure: linear consumed h1_{t-4}
      wait2(t > 0 ? P.f1 + ((t - 1) * 4 + grp) * FSTRIDE : nullptr, 32,
            t >= 4 ? P.fL + ((t - 4) * 4 + grp) * FSTRIDE : nullptr, 2);
      {  // stage h1_{t-1} rows m0..m0+31 -> chunks 0..63 (xor-swizzled)
        const __bf16* src = P.h1 + (size_t)((t + 3) & 3) * BBHH + (size_t)m0 * HH;
        #pragma unroll
        for (int rd = 0; rd < 8; ++rd) {
          int g = rd * 256 + tid, row = g >> 6, cc = g & 63;
          v8bf v = *(const v8bf*)(src + (size_t)row * HH + cc * 8);
          *(v8bf*)(sA + ((size_t)row * 64 + (cc ^ (row & 7))) * 8) = v;
        }
      }
      __syncthreads();
      v16f a0 = {0,0,0,0,0,0,0,0,0,0,0,0,0,0,0,0};
      v16f a1 = {0,0,0,0,0,0,0,0,0,0,0,0,0,0,0,0};
      #pragma unroll
      for (int ks = 0; ks < 32; ks += 2) {        // recurrent half
        v8bf af0 = *(const v8bf*)(abase + ((ks * 2 + khi) ^ h) * 8);
        a0 = mfma32(af0, breg[ks], a0);
        v8bf af1 = *(const v8bf*)(abase + ((ks * 2 + 2 + khi) ^ h) * 8);
        a1 = mfma32(af1, breg[ks + 1], a1);
      }
      wait2(P.f0 + (t * 4 + grp) * FSTRIDE, 16, nullptr, 0);  // h0_t ready
      {  // re-stage same region with h0_t (wait2's barrier fenced the reads)
        const __bf16* src = P.h0 + (size_t)(t & 3) * BBHH + (size_t)m0 * HH;
        #pragma unroll
        for (int rd = 0; rd < 8; ++rd) {
          int g = rd * 256 + tid, row = g >> 6, cc = g & 63;
          v8bf v = *(const v8bf*)(src + (size_t)row * HH + cc * 8);
          *(v8bf*)(sA + ((size_t)row * 64 + (cc ^ (row & 7))) * 8) = v;
        }
      }
      __syncthreads();
      #pragma unroll
      for (int ks = 0; ks < 32; ks += 2) {        // input (h0) half
        v8bf af0 = *(const v8bf*)(abase + ((ks * 2 + khi) ^ h) * 8);
        a0 = mfma32(af0, breg[32 + ks], a0);
        v8bf af1 = *(const v8bf*)(abase + ((ks * 2 + 2 + khi) ^ h) * 8);
        a1 = mfma32(af1, breg[33 + ks], a1);
      }
      __syncthreads();                            // A reads done; reuse as xch
      #pragma unroll
      for (int rg = 0; rg < 16; ++rg) {
        int row = (rg & 3) + 8 * (rg >> 2) + 4 * khi;   // 32x32 C/D [m74/m101]
        xch[row * 132 + wid * 32 + l32] = a0[rg] + a1[rg];
      }
      __syncthreads();
      __bf16* hdst = P.h1 + (size_t)(t & 3) * BBHH;
      #pragma unroll
      for (int k = 0; k < 4; ++k) {
        int rr = rr0 + 8 * k;
        float iv = xch[rr * 132      + jj] + bI;
        float fv = xch[rr * 132 + 32 + jj] + bF;
        float gv = xch[rr * 132 + 64 + jj] + bG;
        float ov = xch[rr * 132 + 96 + jj] + bO;
        float cn = sigm(fv) * creg[k] + sigm(iv) * tanh_fast(gv);
        creg[k] = cn;
        hdst[(size_t)(m0 + rr) * HH + j] = (__bf16)(sigm(ov) * tanh_fast(cn));
      }
      signal(P.f1 + (t * 4 + grp) * FSTRIDE);
    }
  } else if (bid < 192) {
    // =================== LAYER 0 : x_t @ Wi0^T + h0_{t-1} @ Wh0^T =============
    const int k2 = bid - 128;
    const int m0 = (k2 >> 4) * 64;
    const int mt = k2 >> 4;
    const int j0 = (k2 & 15) * 32;
    const int n  = wid * HH + j0 + l32;
    v8bf breg[36];                               // 144 VGPRs, persistent
    {
      const __bf16* Wi = P.Wi0 + (size_t)n * IND + khi * 8;
      #pragma unroll
      for (int ks = 0; ks < 4; ++ks) breg[ks] = *(const v8bf*)(Wi + ks * 16);
      const __bf16* Wh = P.Wh0 + (size_t)n * HH + khi * 8;
      #pragma unroll
      for (int ks = 0; ks < 32; ++ks) breg[4 + ks] = *(const v8bf*)(Wh + ks * 16);
    }
    const int jj = tid & 31, rr0 = tid >> 5;
    const int j = j0 + jj;
    const float bI = P.bsum0[j], bF = P.bsum0[HH + j],
                bG = P.bsum0[2 * HH + j], bO = P.bsum0[3 * HH + j];
    float creg[8] = {0.f,0.f,0.f,0.f,0.f,0.f,0.f,0.f};
    const int h = l32 & 7;
    const __bf16* abase = sA + (size_t)l32 * 72 * 8;

    for (int t = 0; t < TT; ++t) {
      wait2(t > 0 ? P.f0 + ((t - 1) * 4 + mt) * FSTRIDE : nullptr, 16,
            t >= 4 ? P.f1 + ((t - 4) * 4 + mt) * FSTRIDE : nullptr, 32);
      const __bf16* h0src = P.h0 + (size_t)((t + 3) & 3) * BBHH;
      __bf16*       hdst  = P.h0 + (size_t)(t & 3) * BBHH;
      #pragma unroll 1
      for (int rt = 0; rt < 2; ++rt) {     // two 32-row sub-passes
        __syncthreads();                   // prev epilogue xch reads done
        {  // stage x_t: 32 rows x 8 chunks (chunks 0..7)
          int row = tid >> 3, cc = tid & 7;
          const __bf16* src = P.xb + (size_t)t * BB * IND + (size_t)(m0 + rt * 32 + row) * IND;
          v8bf v = *(const v8bf*)(src + cc * 8);
          *(v8bf*)(sA + ((size_t)row * 72 + (cc ^ (row & 7))) * 8) = v;
        }
        #pragma unroll
        for (int rd = 0; rd < 8; ++rd) {   // stage h0_{t-1}: chunks 8..71
          int g = rd * 256 + tid, row = g >> 6, cc = g & 63;
          v8bf v = *(const v8bf*)(h0src + (size_t)(m0 + rt * 32 + row) * HH + cc * 8);
          *(v8bf*)(sA + ((size_t)row * 72 + ((8 + cc) ^ (row & 7))) * 8) = v;
        }
        __syncthreads();
        v16f a0 = {0,0,0,0,0,0,0,0,0,0,0,0,0,0,0,0};
        v16f a1 = {0,0,0,0,0,0,0,0,0,0,0,0,0,0,0,0};
        #pragma unroll
        for (int ks = 0; ks < 36; ks += 2) {
          v8bf af0 = *(const v8bf*)(abase + ((ks * 2 + khi) ^ h) * 8);
          a0 = mfma32(af0, breg[ks], a0);
          v8bf af1 = *(const v8bf*)(abase + ((ks * 2 + 2 + khi) ^ h) * 8);
          a1 = mfma32(af1, breg[ks + 1], a1);
        }
        __syncthreads();
        #pragma unroll
        for (int rg = 0; rg < 16; ++rg) {
          int row = (rg & 3) + 8 * (rg >> 2) + 4 * khi;
          xch[row * 132 + wid * 32 + l32] = a0[rg] + a1[rg];
        }
        __syncthreads();
        #pragma unroll
        for (int k = 0; k < 4; ++k) {
          int rr = rr0 + 8 * k;
          float iv = xch[rr * 132      + jj] + bI;
          float fv = xch[rr * 132 + 32 + jj] + bF;
          float gv = xch[rr * 132 + 64 + jj] + bG;
          float ov = xch[rr * 132 + 96 + jj] + bO;
          int ci = rt * 4 + k;
          float cn = sigm(fv) * creg[ci] + sigm(iv) * tanh_fast(gv);
          creg[ci] = cn;
          hdst[(size_t)(m0 + rt * 32 + rr) * HH + j] = (__bf16)(sigm(ov) * tanh_fast(cn));
        }
      }
      signal(P.f0 + (t * 4 + mt) * FSTRIDE);
    }
  } else if (bid < 200) {
    // =================== LINEAR : h1_t @ Wlin^T + blin =========================
    const int q   = bid - 192;
    const int m0  = q * 32;
    const int grp = m0 >> 6;
    const int l16 = lane & 15, quad = lane >> 4;
    const int col = wid * 16 + l16;
    v8bf breg[16];                               // 64 VGPRs, persistent
    {
      const __bf16* W = P.Wlin + (size_t)col * HH + quad * 8;
      #pragma unroll
      for (int kk = 0; kk < 16; ++kk) breg[kk] = *(const v8bf*)(W + kk * 32);
    }
    const float bb = P.blin[col];
    for (int t = 0; t < TT; ++t) {
      wait2(P.f1 + (t * 4 + grp) * FSTRIDE, 32, nullptr, 0);
      #pragma unroll
      for (int rd = 0; rd < 8; ++rd) {           // stage h1_t rows m0..m0+31
        int g = rd * 256 + tid, row = g >> 6, cc = g & 63;
        const __bf16* src = P.h1 + (size_t)(t & 3) * BBHH + (size_t)m0 * HH;
        v8bf v = *(const v8bf*)(src + (size_t)row * HH + cc * 8);
        *(v8bf*)(sA + ((size_t)row * 64 + (cc ^ (row & 7))) * 8) = v;
      }
      __syncthreads();
      v4f acc0 = {0.f,0.f,0.f,0.f}, acc1 = {0.f,0.f,0.f,0.f};
      #pragma unroll
      for (int kk = 0; kk < 16; ++kk) {
        int c8 = kk * 4 + quad;
        int r0 = l16, r1 = 16 + l16;
        v8bf af0 = *(const v8bf*)(sA + ((size_t)r0 * 64 + (c8 ^ (r0 & 7))) * 8);
        acc0 = mfma16(af0, breg[kk], acc0);
        v8bf af1 = *(const v8bf*)(sA + ((size_t)r1 * 64 + (c8 ^ (r1 & 7))) * 8);
        acc1 = mfma16(af1, breg[kk], acc1);
      }
      #pragma unroll
      for (int r = 0; r < 4; ++r) {              // 16x16 C/D: row=quad*4+r, col=l16
        int b0 = m0 + quad * 4 + r;
        P.out[(size_t)b0 * (TT * OD) + (size_t)t * OD + col] = acc0[r] + bb;
        int b1 = m0 + 16 + quad * 4 + r;
        P.out[(size_t)b1 * (TT * OD) + (size_t)t * OD + col] = acc1[r] + bb;
      }
      signal(P.fL + (t * 4 + grp) * FSTRIDE);    // releases h1 slot (back-pressure)
    }
  }
}

// ---------------- host ----------------------------------------------------------
extern "C" void kernel_launch(void* const* d_in, const int* in_sizes, int n_in,
                              void* d_out, int out_size, void* d_ws, size_t ws_size,
                              hipStream_t stream) {
  const float* x    = (const float*)d_in[0];
  const float* Wi0  = (const float*)d_in[1];
  const float* Wh0  = (const float*)d_in[2];
  const float* bi0  = (const float*)d_in[3];
  const float* bh0  = (const float*)d_in[4];
  const float* Wi1  = (const float*)d_in[5];
  const float* Wh1  = (const float*)d_in[6];
  const float* bi1  = (const float*)d_in[7];
  const float* bh1  = (const float*)d_in[8];
  const float* Wlin = (const float*)d_in[9];
  const float* blin = (const float*)d_in[10];

  char* base = (char*)d_ws;
  size_t off = 0;
  auto take = [&](size_t nbytes) {
    void* p = base + off;
    off = (off + nbytes + 255) & ~(size_t)255;
    return p;
  };
  __bf16* xb    = (__bf16*)take(sizeof(__bf16) * (size_t)TT * BB * IND);
  __bf16* Wi0b  = (__bf16*)take(sizeof(__bf16) * 4 * HH * IND);
  __bf16* Wh0b  = (__bf16*)take(sizeof(__bf16) * 4 * HH * HH);
  __bf16* Wi1b  = (__bf16*)take(sizeof(__bf16) * 4 * HH * HH);
  __bf16* Wh1b  = (__bf16*)take(sizeof(__bf16) * 4 * HH * HH);
  __bf16* Wlinb = (__bf16*)take(sizeof(__bf16) * OD * HH);
  float*  bsum0 = (float*)take(sizeof(float) * 4 * HH);
  float*  bsum1 = (float*)take(sizeof(float) * 4 * HH);
  __bf16* h0    = (__bf16*)take(sizeof(__bf16) * 4 * BBHH);
  __bf16* h1    = (__bf16*)take(sizeof(__bf16) * 4 * BBHH);
  int*    flags = (int*)take(sizeof(int) * 3 * TT * 4 * FSTRIDE);

  prep_kernel<<<dim3(1024), dim3(256), 0, stream>>>(
      x, Wi0, Wh0, bi0, bh0, Wi1, Wh1, bi1, bh1, Wlin,
      xb, Wi0b, Wh0b, Wi1b, Wh1b, Wlinb, bsum0, bsum1, h0, h1, flags);

  Params P;
  P.xb = xb; P.Wi0 = Wi0b; P.Wh0 = Wh0b; P.Wi1 = Wi1b; P.Wh1 = Wh1b; P.Wlin = Wlinb;
  P.bsum0 = bsum0; P.bsum1 = bsum1; P.blin = blin;
  P.h0 = h0; P.h1 = h1;
  P.f0 = flags;
  P.f1 = flags + TT * 4 * FSTRIDE;
  P.fL = flags + 2 * TT * 4 * FSTRIDE;
  P.out = (float*)d_out;

  void* kargs[] = { (void*)&P };
  hipError_t err = hipLaunchCooperativeKernel(reinterpret_cast<void*>(lstm_persist),
                                              dim3(200), dim3(256), kargs, 0, stream);
  if (err != hipSuccess) {
    // Flag protocol needs co-residency only: 200 blocks @ 1 block/CU on 256 CUs
    // are all dispatched immediately; plain launch is a safe fallback.
    lstm_persist<<<dim3(200), dim3(256), 0, stream>>>(P);
  }
}

// Round 4
// 4872.788 us; speedup vs baseline: 5.4416x; 3.8944x over previous
//
#include <hip/hip_runtime.h>
#include <hip/hip_bf16.h>

#define TT  512
#define BB  256
#define IND 64
#define HH  512
#define OD  64
#define BBHH (BB * HH)
#define FSTRIDE 32   // ints per flag line (128B)

typedef __bf16 v8bf  __attribute__((ext_vector_type(8)));
typedef float  v4f   __attribute__((ext_vector_type(4)));
typedef float  v16f  __attribute__((ext_vector_type(16)));

struct Params {
  const __bf16 *xb, *Wi0, *Wh0, *Wi1, *Wh1, *Wlin;
  const float  *bsum0, *bsum1, *blin;
  __bf16 *h0, *h1;          // 4-slot ring buffers [4][BB*HH], slot = t & 3
  int *flags;               // per-producer-block: [0..63]=L0, [64..191]=L1, [192..199]=lin
  float *out;               // [BB][TT*OD]
};

__device__ __forceinline__ float sigm(float x) { return 1.f / (1.f + __expf(-x)); }
__device__ __forceinline__ float tanh_fast(float x) {
  float e = __expf(2.f * x);
  return 1.f - 2.f / (e + 1.f);
}
__device__ __forceinline__ v4f mfma16(v8bf a, v8bf b, v4f c) {
  return __builtin_amdgcn_mfma_f32_16x16x32_bf16(a, b, c, 0, 0, 0);
}
__device__ __forceinline__ v16f mfma32(v8bf a, v8bf b, v16f c) {
  return __builtin_amdgcn_mfma_f32_32x32x16_bf16(a, b, c, 0, 0, 0);
}
__device__ __forceinline__ v8bf bc(v4f x) { return __builtin_bit_cast(v8bf, x); }

// Agent-scope (cross-XCD coherent at LLC) data movement — no fences needed.
__device__ __forceinline__ unsigned long long aload8(const unsigned long long* p) {
  return __hip_atomic_load(p, __ATOMIC_RELAXED, __HIP_MEMORY_SCOPE_AGENT);
}
__device__ __forceinline__ void astore8(unsigned long long* p, unsigned long long v) {
  __hip_atomic_store(p, v, __ATOMIC_RELAXED, __HIP_MEMORY_SCOPE_AGENT);
}
// Per-lane flag poll: one reader-lane per line, single writer, monotonic value.
__device__ __forceinline__ void pollOne(const int* p, int target) {
  while (__hip_atomic_load(p, __ATOMIC_RELAXED, __HIP_MEMORY_SCOPE_AGENT) < target)
    __builtin_amdgcn_s_sleep(1);
}
// Producer completion: every thread drains its own stores to the coherence
// point, barrier, then leader publishes the flag (relaxed is safe: data is
// already complete at LLC before the flag store issues).
__device__ __forceinline__ void drainAll() {
  asm volatile("s_waitcnt vmcnt(0)" ::: "memory");
  __syncthreads();
}
__device__ __forceinline__ void setFlag(int* f, int v) {
  if (threadIdx.x == 0)
    __hip_atomic_store(f, v, __ATOMIC_RELAXED, __HIP_MEMORY_SCOPE_AGENT);
}

// Stage one 32x512 bf16 matrix (rows base..base+31) into LDS, xor-swizzled
// 16B chunks, via agent-scope 8B loads (coherent w/o fences).
__device__ __forceinline__ void stage32(const __bf16* src, __bf16* dst, int tid) {
  #pragma unroll
  for (int rd = 0; rd < 8; ++rd) {
    int g = rd * 256 + tid, row = g >> 6, cc = g & 63;
    const unsigned long long* p = (const unsigned long long*)(src + (size_t)row * HH + cc * 8);
    unsigned long long tmp[2];
    tmp[0] = aload8(p);
    tmp[1] = aload8(p + 1);
    *(v8bf*)(dst + ((size_t)row * 64 + (cc ^ (row & 7))) * 8) = *(const v8bf*)tmp;
  }
}

// ---------------- prep: fp32 -> bf16, combined biases, zero states/flags -------
__global__ void __launch_bounds__(256) prep_kernel(
    const float* x, const float* Wi0, const float* Wh0, const float* bi0, const float* bh0,
    const float* Wi1, const float* Wh1, const float* bi1, const float* bh1, const float* Wlin,
    __bf16* xb, __bf16* Wi0b, __bf16* Wh0b, __bf16* Wi1b, __bf16* Wh1b, __bf16* Wlinb,
    float* bsum0, float* bsum1, __bf16* h0, __bf16* h1, int* flags) {
  size_t tid = (size_t)blockIdx.x * blockDim.x + threadIdx.x;
  size_t np  = (size_t)gridDim.x * blockDim.x;
  for (size_t i = tid; i < (size_t)TT * BB * IND; i += np) xb[i]    = (__bf16)x[i];
  for (size_t i = tid; i < (size_t)4 * HH * IND;  i += np) Wi0b[i]  = (__bf16)Wi0[i];
  for (size_t i = tid; i < (size_t)4 * HH * HH;   i += np) Wh0b[i]  = (__bf16)Wh0[i];
  for (size_t i = tid; i < (size_t)4 * HH * HH;   i += np) Wi1b[i]  = (__bf16)Wi1[i];
  for (size_t i = tid; i < (size_t)4 * HH * HH;   i += np) Wh1b[i]  = (__bf16)Wh1[i];
  for (size_t i = tid; i < (size_t)OD * HH;       i += np) Wlinb[i] = (__bf16)Wlin[i];
  for (size_t i = tid; i < (size_t)4 * HH; i += np) {
    bsum0[i] = bi0[i] + bh0[i];
    bsum1[i] = bi1[i] + bh1[i];
  }
  for (size_t i = tid; i < (size_t)4 * BBHH; i += np) { h0[i] = (__bf16)0.f; h1[i] = (__bf16)0.f; }
  for (size_t i = tid; i < (size_t)200 * FSTRIDE; i += np) flags[i] = 0;
}

// ---------------- persistent flag-synced kernel --------------------------------
// bid 0..127  : layer1  (8 m-tiles x 32 rows) x (16 j-chunks x 32 cols/gate)
// bid 128..191: layer0  (4 m-tiles x 64 rows) x (16 j-chunks x 32 cols/gate)
// bid 192..199: linear  (8 m-tiles x 32 rows)
// Flags: flags[id*FSTRIDE], one writer each, value = t+1 after finishing step t.
//   L0 block id: (bid-128)        L1 block id: 64+bid        lin id: 192+q
__global__ void __launch_bounds__(256, 1) lstm_persist(Params P) {
  __shared__ __align__(16) __bf16 sA[32 * 72 * 8];   // 36,864 B staging
  __shared__ __align__(16) float  xch[32 * 132];     // 16,896 B gate exchange

  const int bid  = blockIdx.x;
  const int tid  = threadIdx.x;
  const int lane = tid & 63;
  const int wid  = tid >> 6;        // wave = gate (layers) or col-group (linear)
  const int khi  = lane >> 5;       // k-half within a K=16 step
  const int l32  = lane & 31;
  int* FL = P.flags;

  if (bid < 128) {
    // =================== LAYER 1 : h1_{t-1} @ Wh1^T  +  h0_t @ Wi1^T ==========
    const int mt1 = bid >> 4;
    const int m0  = mt1 * 32;
    const int j0  = (bid & 15) * 32;
    const int n   = wid * HH + j0 + l32;         // weight row = gate column
    v4f breg[64];                                // 256 VGPRs, pinned resident
    {
      const __bf16* Wh = P.Wh1 + (size_t)n * HH + khi * 8;
      #pragma unroll
      for (int ks = 0; ks < 32; ++ks) breg[ks]      = *(const v4f*)(Wh + ks * 16);
      const __bf16* Wi = P.Wi1 + (size_t)n * HH + khi * 8;
      #pragma unroll
      for (int ks = 0; ks < 32; ++ks) breg[32 + ks] = *(const v4f*)(Wi + ks * 16);
      #pragma unroll
      for (int i = 0; i < 64; ++i) asm volatile("" : "+v"(breg[i]));
    }
    const int er = tid & 31, ecg = tid >> 5;     // epilogue: row er, cols ecg*4..+3
    const int jc = j0 + ecg * 4;
    const v4f bI = *(const v4f*)(P.bsum1 + jc);
    const v4f bF = *(const v4f*)(P.bsum1 + HH + jc);
    const v4f bG = *(const v4f*)(P.bsum1 + 2 * HH + jc);
    const v4f bO = *(const v4f*)(P.bsum1 + 3 * HH + jc);
    float creg[4] = {0.f, 0.f, 0.f, 0.f};
    const int hsw = l32 & 7;
    const __bf16* abase = sA + (size_t)l32 * 64 * 8;

    for (int t = 0; t < TT; ++t) {
      // h1_{t-1} ready (own m-tile's 16 blocks); linear released slot (t-4)
      if (tid < 16)       pollOne(FL + (64 + mt1 * 16 + tid) * FSTRIDE, t);
      else if (tid == 16) pollOne(FL + (192 + mt1) * FSTRIDE, t - 3);
      __syncthreads();
      stage32(P.h1 + (size_t)((t + 3) & 3) * BBHH + (size_t)m0 * HH, sA, tid);
      __syncthreads();
      v16f a0 = {0,0,0,0,0,0,0,0,0,0,0,0,0,0,0,0};
      v16f a1 = {0,0,0,0,0,0,0,0,0,0,0,0,0,0,0,0};
      #pragma unroll
      for (int ks = 0; ks < 32; ks += 2) {       // recurrent half
        v8bf af0 = *(const v8bf*)(abase + ((ks * 2 + khi) ^ hsw) * 8);
        a0 = mfma32(af0, bc(breg[ks]), a0);
        v8bf af1 = *(const v8bf*)(abase + ((ks * 2 + 2 + khi) ^ hsw) * 8);
        a1 = mfma32(af1, bc(breg[ks + 1]), a1);
      }
      if (tid < 16) pollOne(FL + ((mt1 >> 1) * 16 + tid) * FSTRIDE, t + 1);  // h0_t
      __syncthreads();
      stage32(P.h0 + (size_t)(t & 3) * BBHH + (size_t)m0 * HH, sA, tid);
      __syncthreads();
      #pragma unroll
      for (int ks = 0; ks < 32; ks += 2) {       // input (h0) half
        v8bf af0 = *(const v8bf*)(abase + ((ks * 2 + khi) ^ hsw) * 8);
        a0 = mfma32(af0, bc(breg[32 + ks]), a0);
        v8bf af1 = *(const v8bf*)(abase + ((ks * 2 + 2 + khi) ^ hsw) * 8);
        a1 = mfma32(af1, bc(breg[32 + ks + 1]), a1);
      }
      #pragma unroll
      for (int rg = 0; rg < 16; ++rg) {
        int row = (rg & 3) + 8 * (rg >> 2) + 4 * khi;   // 32x32 C/D [m74/m101]
        xch[row * 132 + wid * 32 + l32] = a0[rg] + a1[rg];
      }
      __syncthreads();
      {
        const float* xr = xch + er * 132 + ecg * 4;
        v4f vi = *(const v4f*)(xr);
        v4f vf = *(const v4f*)(xr + 32);
        v4f vg = *(const v4f*)(xr + 64);
        v4f vo = *(const v4f*)(xr + 96);
        unsigned long long pk = 0;
        #pragma unroll
        for (int q = 0; q < 4; ++q) {
          float cn = sigm(vf[q] + bF[q]) * creg[q] + sigm(vi[q] + bI[q]) * tanh_fast(vg[q] + bG[q]);
          creg[q] = cn;
          __bf16 hb = (__bf16)(sigm(vo[q] + bO[q]) * tanh_fast(cn));
          pk |= (unsigned long long)__builtin_bit_cast(unsigned short, hb) << (16 * q);
        }
        astore8((unsigned long long*)(P.h1 + (size_t)(t & 3) * BBHH
                                      + (size_t)(m0 + er) * HH + jc), pk);
      }
      drainAll();
      setFlag(FL + (64 + bid) * FSTRIDE, t + 1);
    }
  } else if (bid < 192) {
    // =================== LAYER 0 : x_t @ Wi0^T + h0_{t-1} @ Wh0^T =============
    const int b0 = bid - 128;
    const int mt = b0 >> 4;
    const int m0 = mt * 64;
    const int j0 = (b0 & 15) * 32;
    const int n  = wid * HH + j0 + l32;
    v4f breg[36];                                // 144 VGPRs, pinned resident
    {
      const __bf16* Wi = P.Wi0 + (size_t)n * IND + khi * 8;
      #pragma unroll
      for (int ks = 0; ks < 4; ++ks) breg[ks] = *(const v4f*)(Wi + ks * 16);
      const __bf16* Wh = P.Wh0 + (size_t)n * HH + khi * 8;
      #pragma unroll
      for (int ks = 0; ks < 32; ++ks) breg[4 + ks] = *(const v4f*)(Wh + ks * 16);
      #pragma unroll
      for (int i = 0; i < 36; ++i) asm volatile("" : "+v"(breg[i]));
    }
    const int er = tid & 31, ecg = tid >> 5;
    const int jc = j0 + ecg * 4;
    const v4f bI = *(const v4f*)(P.bsum0 + jc);
    const v4f bF = *(const v4f*)(P.bsum0 + HH + jc);
    const v4f bG = *(const v4f*)(P.bsum0 + 2 * HH + jc);
    const v4f bO = *(const v4f*)(P.bsum0 + 3 * HH + jc);
    float creg[2][4] = {{0.f,0.f,0.f,0.f},{0.f,0.f,0.f,0.f}};
    const int hsw = l32 & 7;
    const __bf16* abase = sA + (size_t)l32 * 72 * 8;

    for (int t = 0; t < TT; ++t) {
      // own group's h0_{t-1}; back-pressure: layer1 read h0_{t-4} (32 blocks)
      if (tid < 16)                    pollOne(FL + (mt * 16 + tid) * FSTRIDE, t);
      else if (tid >= 16 && tid < 48)  pollOne(FL + (64 + mt * 32 + (tid - 16)) * FSTRIDE, t - 3);
      __syncthreads();
      const __bf16* h0src = P.h0 + (size_t)((t + 3) & 3) * BBHH;
      __bf16*       hdst  = P.h0 + (size_t)(t & 3) * BBHH;
      #pragma unroll 1
      for (int rt = 0; rt < 2; ++rt) {           // two 32-row sub-passes
        if (rt) __syncthreads();                 // rt0 epilogue/mfma reads done
        {  // stage x_t: 32 rows x 8 chunks (normal loads; prep-written)
          int row = tid >> 3, cc = tid & 7;
          const __bf16* src = P.xb + (size_t)t * BB * IND
                              + (size_t)(m0 + rt * 32 + row) * IND;
          v8bf v = *(const v8bf*)(src + cc * 8);
          *(v8bf*)(sA + ((size_t)row * 72 + (cc ^ (row & 7))) * 8) = v;
        }
        #pragma unroll
        for (int rd = 0; rd < 8; ++rd) {         // stage h0_{t-1}: chunks 8..71
          int g = rd * 256 + tid, row = g >> 6, cc = g & 63;
          const unsigned long long* p = (const unsigned long long*)
              (h0src + (size_t)(m0 + rt * 32 + row) * HH + cc * 8);
          unsigned long long tmp[2];
          tmp[0] = aload8(p);
          tmp[1] = aload8(p + 1);
          *(v8bf*)(sA + ((size_t)row * 72 + ((8 + cc) ^ (row & 7))) * 8) = *(const v8bf*)tmp;
        }
        __syncthreads();
        v16f a0 = {0,0,0,0,0,0,0,0,0,0,0,0,0,0,0,0};
        v16f a1 = {0,0,0,0,0,0,0,0,0,0,0,0,0,0,0,0};
        #pragma unroll
        for (int ks = 0; ks < 36; ks += 2) {
          v8bf af0 = *(const v8bf*)(abase + ((ks * 2 + khi) ^ hsw) * 8);
          a0 = mfma32(af0, bc(breg[ks]), a0);
          v8bf af1 = *(const v8bf*)(abase + ((ks * 2 + 2 + khi) ^ hsw) * 8);
          a1 = mfma32(af1, bc(breg[ks + 1]), a1);
        }
        #pragma unroll
        for (int rg = 0; rg < 16; ++rg) {
          int row = (rg & 3) + 8 * (rg >> 2) + 4 * khi;
          xch[row * 132 + wid * 32 + l32] = a0[rg] + a1[rg];
        }
        __syncthreads();
        {
          const float* xr = xch + er * 132 + ecg * 4;
          v4f vi = *(const v4f*)(xr);
          v4f vf = *(const v4f*)(xr + 32);
          v4f vg = *(const v4f*)(xr + 64);
          v4f vo = *(const v4f*)(xr + 96);
          unsigned long long pk = 0;
          #pragma unroll
          for (int q = 0; q < 4; ++q) {
            float cn = sigm(vf[q] + bF[q]) * creg[rt][q]
                     + sigm(vi[q] + bI[q]) * tanh_fast(vg[q] + bG[q]);
            creg[rt][q] = cn;
            __bf16 hb = (__bf16)(sigm(vo[q] + bO[q]) * tanh_fast(cn));
            pk |= (unsigned long long)__builtin_bit_cast(unsigned short, hb) << (16 * q);
          }
          astore8((unsigned long long*)(hdst + (size_t)(m0 + rt * 32 + er) * HH + jc), pk);
        }
      }
      drainAll();
      setFlag(FL + b0 * FSTRIDE, t + 1);
    }
  } else if (bid < 200) {
    // =================== LINEAR : h1_t @ Wlin^T + blin =========================
    const int q   = bid - 192;
    const int m0  = q * 32;
    const int l16 = lane & 15, quad = lane >> 4;
    const int col = wid * 16 + l16;
    v4f breg[16];                                // 64 VGPRs, pinned resident
    {
      const __bf16* W = P.Wlin + (size_t)col * HH + quad * 8;
      #pragma unroll
      for (int kk = 0; kk < 16; ++kk) breg[kk] = *(const v4f*)(W + kk * 32);
      #pragma unroll
      for (int i = 0; i < 16; ++i) asm volatile("" : "+v"(breg[i]));
    }
    const float bb = P.blin[col];
    for (int t = 0; t < TT; ++t) {
      if (tid < 16) pollOne(FL + (64 + q * 16 + tid) * FSTRIDE, t + 1);   // h1_t
      __syncthreads();
      stage32(P.h1 + (size_t)(t & 3) * BBHH + (size_t)m0 * HH, sA, tid);
      __syncthreads();
      v4f acc0 = {0.f,0.f,0.f,0.f}, acc1 = {0.f,0.f,0.f,0.f};
      #pragma unroll
      for (int kk = 0; kk < 16; ++kk) {
        int c8 = kk * 4 + quad;
        int r0 = l16, r1 = 16 + l16;
        v8bf af0 = *(const v8bf*)(sA + ((size_t)r0 * 64 + (c8 ^ (r0 & 7))) * 8);
        acc0 = mfma16(af0, bc(breg[kk]), acc0);
        v8bf af1 = *(const v8bf*)(sA + ((size_t)r1 * 64 + (c8 ^ (r1 & 7))) * 8);
        acc1 = mfma16(af1, bc(breg[kk]), acc1);
      }
      #pragma unroll
      for (int r = 0; r < 4; ++r) {              // 16x16 C/D: row=quad*4+r, col=l16
        int b0r = m0 + quad * 4 + r;
        P.out[(size_t)b0r * (TT * OD) + (size_t)t * OD + col] = acc0[r] + bb;
        int b1r = m0 + 16 + quad * 4 + r;
        P.out[(size_t)b1r * (TT * OD) + (size_t)t * OD + col] = acc1[r] + bb;
      }
      drainAll();                                // h1_t reads complete
      setFlag(FL + (192 + q) * FSTRIDE, t + 1);  // release h1 slot
    }
  }
}

// ---------------- host ----------------------------------------------------------
extern "C" void kernel_launch(void* const* d_in, const int* in_sizes, int n_in,
                              void* d_out, int out_size, void* d_ws, size_t ws_size,
                              hipStream_t stream) {
  const float* x    = (const float*)d_in[0];
  const float* Wi0  = (const float*)d_in[1];
  const float* Wh0  = (const float*)d_in[2];
  const float* bi0  = (const float*)d_in[3];
  const float* bh0  = (const float*)d_in[4];
  const float* Wi1  = (const float*)d_in[5];
  const float* Wh1  = (const float*)d_in[6];
  const float* bi1  = (const float*)d_in[7];
  const float* bh1  = (const float*)d_in[8];
  const float* Wlin = (const float*)d_in[9];
  const float* blin = (const float*)d_in[10];

  char* base = (char*)d_ws;
  size_t off = 0;
  auto take = [&](size_t nbytes) {
    void* p = base + off;
    off = (off + nbytes + 255) & ~(size_t)255;
    return p;
  };
  __bf16* xb    = (__bf16*)take(sizeof(__bf16) * (size_t)TT * BB * IND);
  __bf16* Wi0b  = (__bf16*)take(sizeof(__bf16) * 4 * HH * IND);
  __bf16* Wh0b  = (__bf16*)take(sizeof(__bf16) * 4 * HH * HH);
  __bf16* Wi1b  = (__bf16*)take(sizeof(__bf16) * 4 * HH * HH);
  __bf16* Wh1b  = (__bf16*)take(sizeof(__bf16) * 4 * HH * HH);
  __bf16* Wlinb = (__bf16*)take(sizeof(__bf16) * OD * HH);
  float*  bsum0 = (float*)take(sizeof(float) * 4 * HH);
  float*  bsum1 = (float*)take(sizeof(float) * 4 * HH);
  __bf16* h0    = (__bf16*)take(sizeof(__bf16) * 4 * BBHH);
  __bf16* h1    = (__bf16*)take(sizeof(__bf16) * 4 * BBHH);
  int*    flags = (int*)take(sizeof(int) * 200 * FSTRIDE);

  prep_kernel<<<dim3(1024), dim3(256), 0, stream>>>(
      x, Wi0, Wh0, bi0, bh0, Wi1, Wh1, bi1, bh1, Wlin,
      xb, Wi0b, Wh0b, Wi1b, Wh1b, Wlinb, bsum0, bsum1, h0, h1, flags);

  Params P;
  P.xb = xb; P.Wi0 = Wi0b; P.Wh0 = Wh0b; P.Wi1 = Wi1b; P.Wh1 = Wh1b; P.Wlin = Wlinb;
  P.bsum0 = bsum0; P.bsum1 = bsum1; P.blin = blin;
  P.h0 = h0; P.h1 = h1;
  P.flags = flags;
  P.out = (float*)d_out;

  void* kargs[] = { (void*)&P };
  hipError_t err = hipLaunchCooperativeKernel(reinterpret_cast<void*>(lstm_persist),
                                              dim3(200), dim3(256), kargs, 0, stream);
  if (err != hipSuccess) {
    // Flag protocol needs co-residency only: 200 blocks @ 1 block/CU on 256 CUs.
    lstm_persist<<<dim3(200), dim3(256), 0, stream>>>(P);
  }
}